// Round 1
// baseline (1261.483 us; speedup 1.0000x reference)
//
#include <hip/hip_runtime.h>
#include <hip/hip_bf16.h>

// ---------------------------------------------------------------------------
// TransformerEncoderLayer: LN -> MHA(causal) -> +res -> LN -> [in_w -> dwconv
// -> silu -> xp_w -> sequential scan -> repeat+res -> out_w] -> +res -> LN ->
// FFN(gelu) -> +res.
// All matmuls: bf16 MFMA 16x16x32, f32 accumulate. Residual stream kept f32.
// Workspace map (bytes, MB = 2^20):  total ~125 MB
//   [0,36M)    transposed bf16 weights (WqT..fc2T)
//   [36M,44M)  hbf   (LN output, reused for h1/h2/h3)
//   [44M,60M)  x2 f32
//   [60M,76M)  x3 f32
//   [76M,108M) region R: q/k/v/attn (8MB each) -> xr (32MB) -> ffn (32MB)
//   [108M,124M) region S: xm2 (16MB) -> y (16MB)
//   [124M,~125M) xdbl f32, hs f32
// ---------------------------------------------------------------------------

#define SEQ     2048
#define BATCH   2
#define MROWS   4096      // BATCH*SEQ
#define DMODEL  1024
#define DINNER  2048
#define DFF     4096

typedef __attribute__((ext_vector_type(8))) short bf16x8;
typedef __attribute__((ext_vector_type(4))) float f32x4;

__device__ __forceinline__ unsigned short f2b(float x){
    __hip_bfloat16 h = __float2bfloat16(x);
    return *reinterpret_cast<unsigned short*>(&h);
}
__device__ __forceinline__ float b2f(unsigned short u){
    __hip_bfloat16 h;
    *reinterpret_cast<unsigned short*>(&h) = u;
    return __bfloat162float(h);
}
__device__ __forceinline__ float gelu_f(float v){
    float u = 0.7978845608f*(v + 0.044715f*v*v*v);
    float e = __expf(2.f*u);
    float th = 1.f - 2.f*__builtin_amdgcn_rcpf(e + 1.f);
    return 0.5f*v*(1.f + th);
}

// ---------------- transpose + cast: W (KxN f32) -> Wt (NxK bf16) ----------
__global__ __launch_bounds__(256) void transpose_cast(
    const float* __restrict__ W, unsigned short* __restrict__ Wt, int K, int N)
{
    __shared__ float t[64*65];
    int n0 = blockIdx.x*64, k0 = blockIdx.y*64;
    int c = threadIdx.x & 63, r0 = threadIdx.x >> 6;
    #pragma unroll
    for (int rr = 0; rr < 64; rr += 4)
        t[(rr+r0)*65 + c] = W[(size_t)(k0+rr+r0)*N + n0 + c];
    __syncthreads();
    #pragma unroll
    for (int rr = 0; rr < 64; rr += 4)
        Wt[(size_t)(n0+rr+r0)*K + k0 + c] = f2b(t[c*65 + rr + r0]);
}

// ---------------- layernorm row=1024, f32 in -> bf16 out ------------------
__global__ __launch_bounds__(256) void layernorm_bf16(
    const float* __restrict__ x, const float* __restrict__ g,
    const float* __restrict__ b, unsigned short* __restrict__ out)
{
    int row = blockIdx.x;
    const float4* xr = (const float4*)(x + (size_t)row*DMODEL);
    int tid = threadIdx.x;
    float4 xv = xr[tid];
    float s  = xv.x + xv.y + xv.z + xv.w;
    float ss = xv.x*xv.x + xv.y*xv.y + xv.z*xv.z + xv.w*xv.w;
    #pragma unroll
    for (int d = 32; d > 0; d >>= 1){ s += __shfl_xor(s,d); ss += __shfl_xor(ss,d); }
    __shared__ float sm[8];
    int wv = tid>>6, ln = tid&63;
    if (ln == 0){ sm[wv] = s; sm[4+wv] = ss; }
    __syncthreads();
    s  = sm[0]+sm[1]+sm[2]+sm[3];
    ss = sm[4]+sm[5]+sm[6]+sm[7];
    float mean = s*(1.f/DMODEL);
    float var  = ss*(1.f/DMODEL) - mean*mean;
    float rstd = rsqrtf(var + 1e-5f);
    float4 gv = ((const float4*)g)[tid];
    float4 bv = ((const float4*)b)[tid];
    ushort4 o;
    o.x = f2b((xv.x-mean)*rstd*gv.x + bv.x);
    o.y = f2b((xv.y-mean)*rstd*gv.y + bv.y);
    o.z = f2b((xv.z-mean)*rstd*gv.z + bv.z);
    o.w = f2b((xv.w-mean)*rstd*gv.w + bv.w);
    ((ushort4*)(out + (size_t)row*DMODEL))[tid] = o;
}

// ---------------- GEMM: C[M,N] = act(A[M,K] @ Bt[N,K]^T + bias) (+res) ----
// A, Bt bf16 row-major. 128x128 tile, 4 waves, each 64x64. BK=64.
template<int OUT_BF16, int HAS_RES, int ACT>
__global__ __launch_bounds__(256,2) void gemm_bt(
    const unsigned short* __restrict__ A, const unsigned short* __restrict__ Bt,
    const float* __restrict__ bias, const float* __restrict__ res,
    void* __restrict__ outp, int Ndim, int Kdim)
{
    __shared__ unsigned short As[128*72];   // row stride 72 (pad 8) -> 144B
    __shared__ unsigned short Bs[128*72];
    int tid = threadIdx.x;
    int lane = tid & 63, wv = tid >> 6;
    int l15 = lane & 15, quad = lane >> 4;
    int m0 = blockIdx.y*128, n0 = blockIdx.x*128;
    int mo = (wv>>1)*64, no = (wv&1)*64;
    f32x4 zz = {0.f,0.f,0.f,0.f};
    f32x4 acc[4][4];
    #pragma unroll
    for (int i=0;i<4;++i)
      #pragma unroll
      for (int j=0;j<4;++j) acc[i][j] = zz;

    for (int k0 = 0; k0 < Kdim; k0 += 64){
        #pragma unroll
        for (int i=0;i<4;++i){
            int cch = tid + i*256;
            int r = cch >> 3, cc = cch & 7;
            *(uint4*)(&As[r*72 + cc*8]) = *(const uint4*)(A  + (size_t)(m0+r)*Kdim + k0 + cc*8);
            *(uint4*)(&Bs[r*72 + cc*8]) = *(const uint4*)(Bt + (size_t)(n0+r)*Kdim + k0 + cc*8);
        }
        __syncthreads();
        #pragma unroll
        for (int kc=0;kc<2;++kc){
            bf16x8 af[4], bfr[4];
            #pragma unroll
            for (int t=0;t<4;++t){
                af[t]  = *(const bf16x8*)(&As[(mo + t*16 + l15)*72 + kc*32 + quad*8]);
                bfr[t] = *(const bf16x8*)(&Bs[(no + t*16 + l15)*72 + kc*32 + quad*8]);
            }
            #pragma unroll
            for (int mt=0;mt<4;++mt)
              #pragma unroll
              for (int nt=0;nt<4;++nt)
                acc[mt][nt] = __builtin_amdgcn_mfma_f32_16x16x32_bf16(af[mt], bfr[nt], acc[mt][nt], 0,0,0);
        }
        __syncthreads();
    }
    #pragma unroll
    for (int mt=0;mt<4;++mt){
      #pragma unroll
      for (int nt=0;nt<4;++nt){
        int gn = n0 + no + nt*16 + l15;
        float bval = bias[gn];
        #pragma unroll
        for (int r=0;r<4;++r){
            int gm = m0 + mo + mt*16 + quad*4 + r;
            size_t off = (size_t)gm*Ndim + gn;
            float v = acc[mt][nt][r] + bval;
            if constexpr (HAS_RES) v += res[off];
            if constexpr (ACT == 1) v = gelu_f(v);
            if constexpr (OUT_BF16) ((unsigned short*)outp)[off] = f2b(v);
            else                    ((float*)outp)[off] = v;
        }
      }
    }
}

// ---------------- flash attention, causal, 16 heads of 64 ------------------
// grid (32 qtiles reversed, 32 bh); block 256 = 4 waves, wave owns 16 q rows.
__global__ __launch_bounds__(256,2) void attn_flash(
    const unsigned short* __restrict__ q, const unsigned short* __restrict__ k,
    const unsigned short* __restrict__ v, unsigned short* __restrict__ attn)
{
    __shared__ unsigned short Qs[64*72];
    __shared__ unsigned short Ks[64*72];
    __shared__ unsigned short Vt[64*72];   // transposed: Vt[d][t]
    __shared__ unsigned short Ps[64*72];   // per-wave 16-row strips
    int bh = blockIdx.y;
    int qt = (int)gridDim.x - 1 - (int)blockIdx.x;   // longest blocks first
    int q0 = qt*64;
    int tid = threadIdx.x, wv = tid>>6, lane = tid&63;
    int l15 = lane&15, quad = lane>>4;
    const size_t base = (size_t)(bh>>4)*SEQ*DMODEL + (size_t)(bh&15)*64;

    #pragma unroll
    for (int i=0;i<2;++i){
        int cch = tid + i*256; int r = cch>>3, cc = cch&7;
        *(uint4*)(&Qs[r*72 + cc*8]) = *(const uint4*)(q + base + (size_t)(q0+r)*DMODEL + cc*8);
    }
    __syncthreads();
    bf16x8 aq0 = *(const bf16x8*)(&Qs[(wv*16 + l15)*72 + quad*8]);
    bf16x8 aq1 = *(const bf16x8*)(&Qs[(wv*16 + l15)*72 + 32 + quad*8]);

    float m_i[4], l_i[4];
    f32x4 zz = {0.f,0.f,0.f,0.f};
    f32x4 o[4];
    #pragma unroll
    for (int r=0;r<4;++r){ m_i[r] = -__builtin_inff(); l_i[r] = 0.f; }
    #pragma unroll
    for (int d=0;d<4;++d) o[d] = zz;

    for (int kt = 0; kt <= qt; ++kt){
        int t0 = kt*64;
        #pragma unroll
        for (int i=0;i<2;++i){
            int cch = tid + i*256; int r = cch>>3, cc = cch&7;
            *(uint4*)(&Ks[r*72 + cc*8]) = *(const uint4*)(k + base + (size_t)(t0+r)*DMODEL + cc*8);
            uint4 vv = *(const uint4*)(v + base + (size_t)(t0+r)*DMODEL + cc*8);
            const unsigned short* pv = (const unsigned short*)&vv;
            #pragma unroll
            for (int j=0;j<8;++j) Vt[(cc*8+j)*72 + r] = pv[j];
        }
        __syncthreads();

        f32x4 sc[4];
        #pragma unroll
        for (int st=0;st<4;++st){
            bf16x8 b0 = *(const bf16x8*)(&Ks[(st*16+l15)*72 + quad*8]);
            bf16x8 b1 = *(const bf16x8*)(&Ks[(st*16+l15)*72 + 32 + quad*8]);
            sc[st] = __builtin_amdgcn_mfma_f32_16x16x32_bf16(aq0, b0, zz, 0,0,0);
            sc[st] = __builtin_amdgcn_mfma_f32_16x16x32_bf16(aq1, b1, sc[st], 0,0,0);
        }
        bool diag = (kt == qt);
        float sval[4][4];
        float mrow[4];
        #pragma unroll
        for (int r=0;r<4;++r) mrow[r] = -__builtin_inff();
        #pragma unroll
        for (int st=0;st<4;++st)
          #pragma unroll
          for (int r=0;r<4;++r){
            float svv = sc[st][r]*0.125f;
            if (diag && (st*16 + l15 > wv*16 + quad*4 + r)) svv = -__builtin_inff();
            sval[st][r] = svv;
            mrow[r] = fmaxf(mrow[r], svv);
          }
        #pragma unroll
        for (int d=1; d<16; d<<=1)
          #pragma unroll
          for (int r=0;r<4;++r) mrow[r] = fmaxf(mrow[r], __shfl_xor(mrow[r], d));
        float alpha[4], rsum[4];
        #pragma unroll
        for (int r=0;r<4;++r){
            float mn = fmaxf(m_i[r], mrow[r]);
            alpha[r] = __expf(m_i[r] - mn);
            m_i[r] = mn;
        }
        #pragma unroll
        for (int st=0;st<4;++st)
          #pragma unroll
          for (int r=0;r<4;++r) sval[st][r] = __expf(sval[st][r] - m_i[r]);
        #pragma unroll
        for (int r=0;r<4;++r) rsum[r] = sval[0][r]+sval[1][r]+sval[2][r]+sval[3][r];
        #pragma unroll
        for (int d=1; d<16; d<<=1)
          #pragma unroll
          for (int r=0;r<4;++r) rsum[r] += __shfl_xor(rsum[r], d);
        #pragma unroll
        for (int r=0;r<4;++r) l_i[r] = l_i[r]*alpha[r] + rsum[r];
        #pragma unroll
        for (int st=0;st<4;++st)
          #pragma unroll
          for (int r=0;r<4;++r)
            Ps[(wv*16 + quad*4 + r)*72 + st*16 + l15] = f2b(sval[st][r]);
        #pragma unroll
        for (int d=0;d<4;++d)
          #pragma unroll
          for (int r=0;r<4;++r) o[d][r] = o[d][r]*alpha[r];
        __syncthreads();
        bf16x8 ap0 = *(const bf16x8*)(&Ps[(wv*16 + l15)*72 + quad*8]);
        bf16x8 ap1 = *(const bf16x8*)(&Ps[(wv*16 + l15)*72 + 32 + quad*8]);
        #pragma unroll
        for (int dtile=0;dtile<4;++dtile){
            bf16x8 b0 = *(const bf16x8*)(&Vt[(dtile*16+l15)*72 + quad*8]);
            bf16x8 b1 = *(const bf16x8*)(&Vt[(dtile*16+l15)*72 + 32 + quad*8]);
            o[dtile] = __builtin_amdgcn_mfma_f32_16x16x32_bf16(ap0, b0, o[dtile], 0,0,0);
            o[dtile] = __builtin_amdgcn_mfma_f32_16x16x32_bf16(ap1, b1, o[dtile], 0,0,0);
        }
        __syncthreads();
    }
    #pragma unroll
    for (int r=0;r<4;++r){
        float inv = 1.f/l_i[r];
        int gm = q0 + wv*16 + quad*4 + r;
        #pragma unroll
        for (int dtile=0;dtile<4;++dtile)
            attn[base + (size_t)gm*DMODEL + dtile*16 + l15] = f2b(o[dtile][r]*inv);
    }
}

// ---------------- depthwise causal conv(4) + bias + silu -------------------
__global__ __launch_bounds__(256) void conv_silu(
    const unsigned short* __restrict__ xr, const float* __restrict__ cw,
    const float* __restrict__ cb, unsigned short* __restrict__ xm2)
{
    int idx = blockIdx.x*256 + threadIdx.x;   // over 4096 * 1024 channel-pairs
    int r  = idx >> 10;
    int c2 = (idx & 1023)*2;
    int s  = r & (SEQ-1);
    float4 w0 = *(const float4*)(cw + c2*4);
    float4 w1 = *(const float4*)(cw + (c2+1)*4);
    float w0a[4] = {w0.x,w0.y,w0.z,w0.w};
    float w1a[4] = {w1.x,w1.y,w1.z,w1.w};
    float a0 = cb[c2], a1 = cb[c2+1];
    const unsigned short* xrow = xr + (size_t)r*DFF + c2;
    #pragma unroll
    for (int j=0;j<4;++j){
        int sp = s - 3 + j;
        if (sp >= 0){
            int off = (j-3)*DFF;
            unsigned int u = *(const unsigned int*)(xrow + off);
            a0 += w0a[j]*b2f(u & 0xffff);
            a1 += w1a[j]*b2f(u >> 16);
        }
    }
    float s0 = a0 * __builtin_amdgcn_rcpf(1.f + __expf(-a0));
    float s1 = a1 * __builtin_amdgcn_rcpf(1.f + __expf(-a1));
    unsigned int op = (unsigned int)f2b(s0) | ((unsigned int)f2b(s1) << 16);
    *(unsigned int*)(xm2 + (size_t)r*DINNER + c2) = op;
}

// ---------------- xdbl = xm2 @ xp_w + xp_b  (N=32, K=2048) -----------------
__global__ __launch_bounds__(256) void xp_gemm(
    const unsigned short* __restrict__ xm2, const float* __restrict__ w,
    const float* __restrict__ bias, float* __restrict__ xdbl)
{
    int tid = threadIdx.x;
    int lr = tid >> 5, n = tid & 31;
    int row = blockIdx.x*8 + lr;
    const unsigned short* ar = xm2 + (size_t)row*DINNER;
    float acc = bias[n];
    #pragma unroll 4
    for (int k2 = 0; k2 < DINNER; k2 += 2){
        unsigned int u = *(const unsigned int*)(ar + k2);
        acc += b2f(u & 0xffff)*w[k2*32 + n] + b2f(u >> 16)*w[(k2+1)*32 + n];
    }
    xdbl[(size_t)row*32 + n] = acc;
}

// ---------------- sequential scan: h = tanh(h@At^T) + b*h + c --------------
__global__ __launch_bounds__(256) void scan_k(
    const float* __restrict__ xdbl, const float* __restrict__ dt,
    const float* __restrict__ A, float* __restrict__ hs)
{
    __shared__ float Ats[256*20];   // row (p*16+i), stride 20 (16B-aligned rows)
    __shared__ float bc[128*32];    // 64 steps x 2 batches x 32 vals
    int tid = threadIdx.x;
    {
        int p = tid >> 4, i = tid & 15;
        float dtp = __expf(dt[p]);
        #pragma unroll
        for (int j=0;j<16;++j) Ats[tid*20 + j] = __expf(dtp * A[i*16 + j]);
    }
    __syncthreads();
    int lane = tid & 63;
    int b = (lane >> 4) & 1, i = lane & 15;
    bool act = (tid < 32);
    float h[16];
    #pragma unroll
    for (int j=0;j<16;++j) h[j] = 0.f;
    float hown = 0.f;
    for (int chunk = 0; chunk < 32; ++chunk){
        #pragma unroll
        for (int t=0;t<16;++t){
            int e = tid + t*256;
            int st = e >> 6, rest = e & 63;
            int bb = rest >> 5, col = rest & 31;
            bc[(st*2+bb)*32 + col] = xdbl[(size_t)(bb*SEQ + chunk*64 + st)*32 + col];
        }
        __syncthreads();
        if (act){
            for (int st = 0; st < 64; ++st){
                int p = st & 15;
                const float4* Ar = (const float4*)&Ats[(p*16 + i)*20];
                float4 A0 = Ar[0], A1 = Ar[1], A2 = Ar[2], A3 = Ar[3];
                float bvv = bc[(st*2+b)*32 + i];
                float cvv = bc[(st*2+b)*32 + 16 + i];
                float acc0 = A0.x*h[0] + A0.y*h[1] + A0.z*h[2] + A0.w*h[3];
                float acc1 = A1.x*h[4] + A1.y*h[5] + A1.z*h[6] + A1.w*h[7];
                float acc2 = A2.x*h[8] + A2.y*h[9] + A2.z*h[10] + A2.w*h[11];
                float acc3 = A3.x*h[12] + A3.y*h[13] + A3.z*h[14] + A3.w*h[15];
                float accv = (acc0+acc1) + (acc2+acc3);
                float e2 = __expf(2.f*accv);
                float th = 1.f - 2.f*__builtin_amdgcn_rcpf(e2 + 1.f);
                float hn = th + bvv*hown + cvv;
                hown = hn;
                hs[(size_t)(b*SEQ + chunk*64 + st)*16 + i] = hn;
                #pragma unroll
                for (int j=0;j<16;++j) h[j] = __shfl(hn, (lane & 48) | j);
            }
        }
        __syncthreads();
    }
}

// ---------------- y = repeat(hs,128) + res (bf16) --------------------------
__global__ __launch_bounds__(256) void y_assemble(
    const float* __restrict__ hs, const unsigned short* __restrict__ xr,
    unsigned short* __restrict__ y)
{
    int idx = blockIdx.x*256 + threadIdx.x;
    int r = idx >> 10;
    int c2 = (idx & 1023)*2;
    unsigned int u = *(const unsigned int*)(xr + (size_t)r*DFF + DINNER + c2);
    float h0 = hs[(size_t)r*16 + (c2 >> 7)];
    float y0 = h0 + b2f(u & 0xffff);
    float y1 = h0 + b2f(u >> 16);
    *(unsigned int*)(y + (size_t)r*DINNER + c2) =
        (unsigned int)f2b(y0) | ((unsigned int)f2b(y1) << 16);
}

// ---------------------------------------------------------------------------
extern "C" void kernel_launch(void* const* d_in, const int* in_sizes, int n_in,
                              void* d_out, int out_size, void* d_ws, size_t ws_size,
                              hipStream_t stream)
{
    (void)in_sizes; (void)n_in; (void)out_size; (void)ws_size;
    const float* x     = (const float*)d_in[0];
    const float* ln1_g = (const float*)d_in[1];
    const float* ln1_b = (const float*)d_in[2];
    const float* Wq    = (const float*)d_in[3];
    const float* bq    = (const float*)d_in[4];
    const float* Wk    = (const float*)d_in[5];
    const float* bk    = (const float*)d_in[6];
    const float* Wv    = (const float*)d_in[7];
    const float* bv    = (const float*)d_in[8];
    const float* Wo    = (const float*)d_in[9];
    const float* bo    = (const float*)d_in[10];
    const float* ln2_g = (const float*)d_in[11];
    const float* ln2_b = (const float*)d_in[12];
    const float* in_w  = (const float*)d_in[13];
    const float* in_b  = (const float*)d_in[14];
    const float* conv_w= (const float*)d_in[15];
    const float* conv_b= (const float*)d_in[16];
    const float* xp_w  = (const float*)d_in[17];
    const float* xp_b  = (const float*)d_in[18];
    const float* dt    = (const float*)d_in[19];
    const float* A     = (const float*)d_in[20];
    const float* out_w = (const float*)d_in[22];
    const float* out_b = (const float*)d_in[23];
    const float* ln3_g = (const float*)d_in[24];
    const float* ln3_b = (const float*)d_in[25];
    const float* fc1_w = (const float*)d_in[26];
    const float* fc1_b = (const float*)d_in[27];
    const float* fc2_w = (const float*)d_in[28];
    const float* fc2_b = (const float*)d_in[29];

    char* ws = (char*)d_ws;
    const size_t MB = 1ull << 20;
    unsigned short* WqT  = (unsigned short*)(ws + 0*MB);
    unsigned short* WkT  = (unsigned short*)(ws + 2*MB);
    unsigned short* WvT  = (unsigned short*)(ws + 4*MB);
    unsigned short* WoT  = (unsigned short*)(ws + 6*MB);
    unsigned short* inT  = (unsigned short*)(ws + 8*MB);
    unsigned short* outT = (unsigned short*)(ws + 16*MB);
    unsigned short* f1T  = (unsigned short*)(ws + 20*MB);
    unsigned short* f2T  = (unsigned short*)(ws + 28*MB);
    unsigned short* hbf  = (unsigned short*)(ws + 36*MB);
    float*          x2   = (float*)(ws + 44*MB);
    float*          x3   = (float*)(ws + 60*MB);
    unsigned short* qb   = (unsigned short*)(ws + 76*MB);
    unsigned short* kb   = (unsigned short*)(ws + 84*MB);
    unsigned short* vb   = (unsigned short*)(ws + 92*MB);
    unsigned short* attnb= (unsigned short*)(ws + 100*MB);
    unsigned short* xr   = (unsigned short*)(ws + 76*MB);   // reuse after attn
    unsigned short* ffn  = (unsigned short*)(ws + 76*MB);   // reuse after y
    unsigned short* xm2  = (unsigned short*)(ws + 108*MB);
    unsigned short* yb   = (unsigned short*)(ws + 108*MB);  // reuse after xp
    float*          xdbl = (float*)(ws + 124*MB);
    float*          hsb  = (float*)(ws + 124*MB + 512*1024);

    dim3 blk(256);
    transpose_cast<<<dim3(16,16), blk, 0, stream>>>(Wq, WqT, 1024, 1024);
    transpose_cast<<<dim3(16,16), blk, 0, stream>>>(Wk, WkT, 1024, 1024);
    transpose_cast<<<dim3(16,16), blk, 0, stream>>>(Wv, WvT, 1024, 1024);
    transpose_cast<<<dim3(16,16), blk, 0, stream>>>(Wo, WoT, 1024, 1024);
    transpose_cast<<<dim3(64,16), blk, 0, stream>>>(in_w, inT, 1024, 4096);
    transpose_cast<<<dim3(16,32), blk, 0, stream>>>(out_w, outT, 2048, 1024);
    transpose_cast<<<dim3(64,16), blk, 0, stream>>>(fc1_w, f1T, 1024, 4096);
    transpose_cast<<<dim3(16,64), blk, 0, stream>>>(fc2_w, f2T, 4096, 1024);

    layernorm_bf16<<<MROWS, blk, 0, stream>>>(x, ln1_g, ln1_b, hbf);
    gemm_bt<1,0,0><<<dim3(8,32),  blk, 0, stream>>>(hbf, WqT, bq, nullptr, qb, 1024, 1024);
    gemm_bt<1,0,0><<<dim3(8,32),  blk, 0, stream>>>(hbf, WkT, bk, nullptr, kb, 1024, 1024);
    gemm_bt<1,0,0><<<dim3(8,32),  blk, 0, stream>>>(hbf, WvT, bv, nullptr, vb, 1024, 1024);
    attn_flash<<<dim3(32,32), blk, 0, stream>>>(qb, kb, vb, attnb);
    gemm_bt<0,1,0><<<dim3(8,32),  blk, 0, stream>>>(attnb, WoT, bo, x, x2, 1024, 1024);
    layernorm_bf16<<<MROWS, blk, 0, stream>>>(x2, ln2_g, ln2_b, hbf);
    gemm_bt<1,0,0><<<dim3(32,32), blk, 0, stream>>>(hbf, inT, in_b, nullptr, xr, 4096, 1024);
    conv_silu<<<16384, blk, 0, stream>>>(xr, conv_w, conv_b, xm2);
    xp_gemm<<<512, blk, 0, stream>>>(xm2, xp_w, xp_b, xdbl);
    scan_k<<<1, blk, 0, stream>>>(xdbl, dt, A, hsb);
    y_assemble<<<16384, blk, 0, stream>>>(hsb, xr, yb);
    gemm_bt<0,1,0><<<dim3(8,32),  blk, 0, stream>>>(yb, outT, out_b, x2, x3, 1024, 2048);
    layernorm_bf16<<<MROWS, blk, 0, stream>>>(x3, ln3_g, ln3_b, hbf);
    gemm_bt<1,0,1><<<dim3(32,32), blk, 0, stream>>>(hbf, f1T, fc1_b, nullptr, ffn, 4096, 1024);
    gemm_bt<0,1,0><<<dim3(8,32),  blk, 0, stream>>>(ffn, f2T, fc2_b, x3, (float*)d_out, 1024, 4096);
}

// Round 2
// 1135.930 us; speedup vs baseline: 1.1105x; 1.1105x over previous
//
#include <hip/hip_runtime.h>
#include <hip/hip_bf16.h>

// ---------------------------------------------------------------------------
// TransformerEncoderLayer. R2 changes vs R1:
//  * gemm_bt: global->LDS staging via __builtin_amdgcn_global_load_lds w=16
//    (m97 pattern, unpadded 64-elem LDS stride).
//  * scan_k: DPP row_ror matvec (VALU, no LDS pipe on the serial path),
//    probe-derived column order (rotation-direction proof), weight/bc
//    prefetch one step ahead, one wave per batch.
// ---------------------------------------------------------------------------

#define SEQ     2048
#define BATCH   2
#define MROWS   4096      // BATCH*SEQ
#define DMODEL  1024
#define DINNER  2048
#define DFF     4096

typedef __attribute__((ext_vector_type(8))) short bf16x8;
typedef __attribute__((ext_vector_type(4))) float f32x4;

__device__ __forceinline__ unsigned short f2b(float x){
    __hip_bfloat16 h = __float2bfloat16(x);
    return *reinterpret_cast<unsigned short*>(&h);
}
__device__ __forceinline__ float b2f(unsigned short u){
    __hip_bfloat16 h;
    *reinterpret_cast<unsigned short*>(&h) = u;
    return __bfloat162float(h);
}
__device__ __forceinline__ float gelu_f(float v){
    float u = 0.7978845608f*(v + 0.044715f*v*v*v);
    float e = __expf(2.f*u);
    float th = 1.f - 2.f*__builtin_amdgcn_rcpf(e + 1.f);
    return 0.5f*v*(1.f + th);
}
__device__ __forceinline__ void gload16(const unsigned short* g, unsigned short* l){
    __builtin_amdgcn_global_load_lds(
        (const __attribute__((address_space(1))) void*)g,
        (__attribute__((address_space(3))) void*)l, 16, 0, 0);
}
template<int CTRL>
__device__ __forceinline__ float dppf(float x){
    int r = __builtin_amdgcn_mov_dpp(__builtin_bit_cast(int, x), CTRL, 0xf, 0xf, false);
    return __builtin_bit_cast(float, r);
}
template<int CTRL>
__device__ __forceinline__ int dppi(int x){
    return __builtin_amdgcn_mov_dpp(x, CTRL, 0xf, 0xf, false);
}

// ---------------- transpose + cast: W (KxN f32) -> Wt (NxK bf16) ----------
__global__ __launch_bounds__(256) void transpose_cast(
    const float* __restrict__ W, unsigned short* __restrict__ Wt, int K, int N)
{
    __shared__ float t[64*65];
    int n0 = blockIdx.x*64, k0 = blockIdx.y*64;
    int c = threadIdx.x & 63, r0 = threadIdx.x >> 6;
    #pragma unroll
    for (int rr = 0; rr < 64; rr += 4)
        t[(rr+r0)*65 + c] = W[(size_t)(k0+rr+r0)*N + n0 + c];
    __syncthreads();
    #pragma unroll
    for (int rr = 0; rr < 64; rr += 4)
        Wt[(size_t)(n0+rr+r0)*K + k0 + c] = f2b(t[c*65 + rr + r0]);
}

// ---------------- layernorm row=1024, f32 in -> bf16 out ------------------
__global__ __launch_bounds__(256) void layernorm_bf16(
    const float* __restrict__ x, const float* __restrict__ g,
    const float* __restrict__ b, unsigned short* __restrict__ out)
{
    int row = blockIdx.x;
    const float4* xr = (const float4*)(x + (size_t)row*DMODEL);
    int tid = threadIdx.x;
    float4 xv = xr[tid];
    float s  = xv.x + xv.y + xv.z + xv.w;
    float ss = xv.x*xv.x + xv.y*xv.y + xv.z*xv.z + xv.w*xv.w;
    #pragma unroll
    for (int d = 32; d > 0; d >>= 1){ s += __shfl_xor(s,d); ss += __shfl_xor(ss,d); }
    __shared__ float sm[8];
    int wv = tid>>6, ln = tid&63;
    if (ln == 0){ sm[wv] = s; sm[4+wv] = ss; }
    __syncthreads();
    s  = sm[0]+sm[1]+sm[2]+sm[3];
    ss = sm[4]+sm[5]+sm[6]+sm[7];
    float mean = s*(1.f/DMODEL);
    float var  = ss*(1.f/DMODEL) - mean*mean;
    float rstd = rsqrtf(var + 1e-5f);
    float4 gv = ((const float4*)g)[tid];
    float4 bv = ((const float4*)b)[tid];
    ushort4 o;
    o.x = f2b((xv.x-mean)*rstd*gv.x + bv.x);
    o.y = f2b((xv.y-mean)*rstd*gv.y + bv.y);
    o.z = f2b((xv.z-mean)*rstd*gv.z + bv.z);
    o.w = f2b((xv.w-mean)*rstd*gv.w + bv.w);
    ((ushort4*)(out + (size_t)row*DMODEL))[tid] = o;
}

// ---------------- GEMM: C[M,N] = act(A[M,K] @ Bt[N,K]^T + bias) (+res) ----
// 128x128 tile, 4 waves, each 64x64. BK=64. global_load_lds staging (m97).
template<int OUT_BF16, int HAS_RES, int ACT>
__global__ __launch_bounds__(256,2) void gemm_bt(
    const unsigned short* __restrict__ A, const unsigned short* __restrict__ Bt,
    const float* __restrict__ bias, const float* __restrict__ res,
    void* __restrict__ outp, int Ndim, int Kdim)
{
    __shared__ unsigned short As[128*64];   // unpadded: required by global_load_lds
    __shared__ unsigned short Bs[128*64];
    int tid = threadIdx.x;
    int lane = tid & 63, wv = tid >> 6;
    int l15 = lane & 15, quad = lane >> 4;
    int m0 = blockIdx.y*128, n0 = blockIdx.x*128;
    int mo = (wv>>1)*64, no = (wv&1)*64;
    int rsub = (lane >> 3);          // 0..7
    int cc8  = (lane & 7)*8;         // element col within 64
    f32x4 zz = {0.f,0.f,0.f,0.f};
    f32x4 acc[4][4];
    #pragma unroll
    for (int i=0;i<4;++i)
      #pragma unroll
      for (int j=0;j<4;++j) acc[i][j] = zz;

    for (int k0 = 0; k0 < Kdim; k0 += 64){
        const unsigned short* Ab = A  + (size_t)(m0 + wv*32 + rsub)*Kdim + k0 + cc8;
        const unsigned short* Bb = Bt + (size_t)(n0 + wv*32 + rsub)*Kdim + k0 + cc8;
        #pragma unroll
        for (int i=0;i<4;++i){
            gload16(Ab + (size_t)(i*8)*Kdim, &As[(wv*32 + i*8)*64]);
            gload16(Bb + (size_t)(i*8)*Kdim, &Bs[(wv*32 + i*8)*64]);
        }
        __syncthreads();
        #pragma unroll
        for (int kc=0;kc<2;++kc){
            bf16x8 af[4], bfr[4];
            #pragma unroll
            for (int t=0;t<4;++t){
                af[t]  = *(const bf16x8*)(&As[(mo + t*16 + l15)*64 + kc*32 + quad*8]);
                bfr[t] = *(const bf16x8*)(&Bs[(no + t*16 + l15)*64 + kc*32 + quad*8]);
            }
            #pragma unroll
            for (int mt=0;mt<4;++mt)
              #pragma unroll
              for (int nt=0;nt<4;++nt)
                acc[mt][nt] = __builtin_amdgcn_mfma_f32_16x16x32_bf16(af[mt], bfr[nt], acc[mt][nt], 0,0,0);
        }
        __syncthreads();
    }
    #pragma unroll
    for (int mt=0;mt<4;++mt){
      #pragma unroll
      for (int nt=0;nt<4;++nt){
        int gn = n0 + no + nt*16 + l15;
        float bval = bias[gn];
        #pragma unroll
        for (int r=0;r<4;++r){
            int gm = m0 + mo + mt*16 + quad*4 + r;
            size_t off = (size_t)gm*Ndim + gn;
            float v = acc[mt][nt][r] + bval;
            if constexpr (HAS_RES) v += res[off];
            if constexpr (ACT == 1) v = gelu_f(v);
            if constexpr (OUT_BF16) ((unsigned short*)outp)[off] = f2b(v);
            else                    ((float*)outp)[off] = v;
        }
      }
    }
}

// ---------------- flash attention, causal, 16 heads of 64 ------------------
__global__ __launch_bounds__(256,2) void attn_flash(
    const unsigned short* __restrict__ q, const unsigned short* __restrict__ k,
    const unsigned short* __restrict__ v, unsigned short* __restrict__ attn)
{
    __shared__ unsigned short Qs[64*72];
    __shared__ unsigned short Ks[64*72];
    __shared__ unsigned short Vt[64*72];
    __shared__ unsigned short Ps[64*72];
    int bh = blockIdx.y;
    int qt = (int)gridDim.x - 1 - (int)blockIdx.x;
    int q0 = qt*64;
    int tid = threadIdx.x, wv = tid>>6, lane = tid&63;
    int l15 = lane&15, quad = lane>>4;
    const size_t base = (size_t)(bh>>4)*SEQ*DMODEL + (size_t)(bh&15)*64;

    #pragma unroll
    for (int i=0;i<2;++i){
        int cch = tid + i*256; int r = cch>>3, cc = cch&7;
        *(uint4*)(&Qs[r*72 + cc*8]) = *(const uint4*)(q + base + (size_t)(q0+r)*DMODEL + cc*8);
    }
    __syncthreads();
    bf16x8 aq0 = *(const bf16x8*)(&Qs[(wv*16 + l15)*72 + quad*8]);
    bf16x8 aq1 = *(const bf16x8*)(&Qs[(wv*16 + l15)*72 + 32 + quad*8]);

    float m_i[4], l_i[4];
    f32x4 zz = {0.f,0.f,0.f,0.f};
    f32x4 o[4];
    #pragma unroll
    for (int r=0;r<4;++r){ m_i[r] = -__builtin_inff(); l_i[r] = 0.f; }
    #pragma unroll
    for (int d=0;d<4;++d) o[d] = zz;

    for (int kt = 0; kt <= qt; ++kt){
        int t0 = kt*64;
        #pragma unroll
        for (int i=0;i<2;++i){
            int cch = tid + i*256; int r = cch>>3, cc = cch&7;
            *(uint4*)(&Ks[r*72 + cc*8]) = *(const uint4*)(k + base + (size_t)(t0+r)*DMODEL + cc*8);
            uint4 vv = *(const uint4*)(v + base + (size_t)(t0+r)*DMODEL + cc*8);
            const unsigned short* pv = (const unsigned short*)&vv;
            #pragma unroll
            for (int j=0;j<8;++j) Vt[(cc*8+j)*72 + r] = pv[j];
        }
        __syncthreads();

        f32x4 sc[4];
        #pragma unroll
        for (int st=0;st<4;++st){
            bf16x8 b0 = *(const bf16x8*)(&Ks[(st*16+l15)*72 + quad*8]);
            bf16x8 b1 = *(const bf16x8*)(&Ks[(st*16+l15)*72 + 32 + quad*8]);
            sc[st] = __builtin_amdgcn_mfma_f32_16x16x32_bf16(aq0, b0, zz, 0,0,0);
            sc[st] = __builtin_amdgcn_mfma_f32_16x16x32_bf16(aq1, b1, sc[st], 0,0,0);
        }
        bool diag = (kt == qt);
        float sval[4][4];
        float mrow[4];
        #pragma unroll
        for (int r=0;r<4;++r) mrow[r] = -__builtin_inff();
        #pragma unroll
        for (int st=0;st<4;++st)
          #pragma unroll
          for (int r=0;r<4;++r){
            float svv = sc[st][r]*0.125f;
            if (diag && (st*16 + l15 > wv*16 + quad*4 + r)) svv = -__builtin_inff();
            sval[st][r] = svv;
            mrow[r] = fmaxf(mrow[r], svv);
          }
        #pragma unroll
        for (int d=1; d<16; d<<=1)
          #pragma unroll
          for (int r=0;r<4;++r) mrow[r] = fmaxf(mrow[r], __shfl_xor(mrow[r], d));
        float alpha[4], rsum[4];
        #pragma unroll
        for (int r=0;r<4;++r){
            float mn = fmaxf(m_i[r], mrow[r]);
            alpha[r] = __expf(m_i[r] - mn);
            m_i[r] = mn;
        }
        #pragma unroll
        for (int st=0;st<4;++st)
          #pragma unroll
          for (int r=0;r<4;++r) sval[st][r] = __expf(sval[st][r] - m_i[r]);
        #pragma unroll
        for (int r=0;r<4;++r) rsum[r] = sval[0][r]+sval[1][r]+sval[2][r]+sval[3][r];
        #pragma unroll
        for (int d=1; d<16; d<<=1)
          #pragma unroll
          for (int r=0;r<4;++r) rsum[r] += __shfl_xor(rsum[r], d);
        #pragma unroll
        for (int r=0;r<4;++r) l_i[r] = l_i[r]*alpha[r] + rsum[r];
        #pragma unroll
        for (int st=0;st<4;++st)
          #pragma unroll
          for (int r=0;r<4;++r)
            Ps[(wv*16 + quad*4 + r)*72 + st*16 + l15] = f2b(sval[st][r]);
        #pragma unroll
        for (int d=0;d<4;++d)
          #pragma unroll
          for (int r=0;r<4;++r) o[d][r] = o[d][r]*alpha[r];
        __syncthreads();
        bf16x8 ap0 = *(const bf16x8*)(&Ps[(wv*16 + l15)*72 + quad*8]);
        bf16x8 ap1 = *(const bf16x8*)(&Ps[(wv*16 + l15)*72 + 32 + quad*8]);
        #pragma unroll
        for (int dtile=0;dtile<4;++dtile){
            bf16x8 b0 = *(const bf16x8*)(&Vt[(dtile*16+l15)*72 + quad*8]);
            bf16x8 b1 = *(const bf16x8*)(&Vt[(dtile*16+l15)*72 + 32 + quad*8]);
            o[dtile] = __builtin_amdgcn_mfma_f32_16x16x32_bf16(ap0, b0, o[dtile], 0,0,0);
            o[dtile] = __builtin_amdgcn_mfma_f32_16x16x32_bf16(ap1, b1, o[dtile], 0,0,0);
        }
        __syncthreads();
    }
    #pragma unroll
    for (int r=0;r<4;++r){
        float inv = 1.f/l_i[r];
        int gm = q0 + wv*16 + quad*4 + r;
        #pragma unroll
        for (int dtile=0;dtile<4;++dtile)
            attn[base + (size_t)gm*DMODEL + dtile*16 + l15] = f2b(o[dtile][r]*inv);
    }
}

// ---------------- depthwise causal conv(4) + bias + silu -------------------
__global__ __launch_bounds__(256) void conv_silu(
    const unsigned short* __restrict__ xr, const float* __restrict__ cw,
    const float* __restrict__ cb, unsigned short* __restrict__ xm2)
{
    int idx = blockIdx.x*256 + threadIdx.x;
    int r  = idx >> 10;
    int c2 = (idx & 1023)*2;
    int s  = r & (SEQ-1);
    float4 w0 = *(const float4*)(cw + c2*4);
    float4 w1 = *(const float4*)(cw + (c2+1)*4);
    float w0a[4] = {w0.x,w0.y,w0.z,w0.w};
    float w1a[4] = {w1.x,w1.y,w1.z,w1.w};
    float a0 = cb[c2], a1 = cb[c2+1];
    const unsigned short* xrow = xr + (size_t)r*DFF + c2;
    #pragma unroll
    for (int j=0;j<4;++j){
        int sp = s - 3 + j;
        if (sp >= 0){
            int off = (j-3)*DFF;
            unsigned int u = *(const unsigned int*)(xrow + off);
            a0 += w0a[j]*b2f(u & 0xffff);
            a1 += w1a[j]*b2f(u >> 16);
        }
    }
    float s0 = a0 * __builtin_amdgcn_rcpf(1.f + __expf(-a0));
    float s1 = a1 * __builtin_amdgcn_rcpf(1.f + __expf(-a1));
    unsigned int op = (unsigned int)f2b(s0) | ((unsigned int)f2b(s1) << 16);
    *(unsigned int*)(xm2 + (size_t)r*DINNER + c2) = op;
}

// ---------------- xdbl = xm2 @ xp_w + xp_b  (N=32, K=2048) -----------------
__global__ __launch_bounds__(256) void xp_gemm(
    const unsigned short* __restrict__ xm2, const float* __restrict__ w,
    const float* __restrict__ bias, float* __restrict__ xdbl)
{
    int tid = threadIdx.x;
    int lr = tid >> 5, n = tid & 31;
    int row = blockIdx.x*8 + lr;
    const unsigned short* ar = xm2 + (size_t)row*DINNER;
    float acc = bias[n];
    #pragma unroll 4
    for (int k2 = 0; k2 < DINNER; k2 += 2){
        unsigned int u = *(const unsigned int*)(ar + k2);
        acc += b2f(u & 0xffff)*w[k2*32 + n] + b2f(u >> 16)*w[(k2+1)*32 + n];
    }
    xdbl[(size_t)row*32 + n] = acc;
}

// ---------------- sequential scan (DPP matvec) -----------------------------
// h_{t+1}[i] = tanh(sum_j exp(dtp*A[i][j]) h_t[j]) + b_t[i] h_t[i] + c_t[i]
// wave 0 -> batch 0, wave 1 -> batch 1; lanes replicate per 16-lane row.
__device__ __forceinline__ float scan_step(float hprev, const float W[16],
                                           float bv, float cv)
{
    float a0 = hprev;
    float b0 = dppf<0x124>(a0);   // row_ror:4
    float c0 = dppf<0x128>(a0);   // row_ror:8
    float d0 = dppf<0x12c>(a0);   // row_ror:12
    float accA = W[0]*a0, accB = W[4]*b0, accC = W[8]*c0, accD = W[12]*d0;
    float a1 = dppf<0x121>(a0); accA += W[1]*a1;
    float b1 = dppf<0x121>(b0); accB += W[5]*b1;
    float c1 = dppf<0x121>(c0); accC += W[9]*c1;
    float d1 = dppf<0x121>(d0); accD += W[13]*d1;
    float a2 = dppf<0x121>(a1); accA += W[2]*a2;
    float b2 = dppf<0x121>(b1); accB += W[6]*b2;
    float c2 = dppf<0x121>(c1); accC += W[10]*c2;
    float d2 = dppf<0x121>(d1); accD += W[14]*d2;
    float a3 = dppf<0x121>(a2); accA += W[3]*a3;
    float b3 = dppf<0x121>(b2); accB += W[7]*b3;
    float c3 = dppf<0x121>(c2); accC += W[11]*c3;
    float d3 = dppf<0x121>(d2); accD += W[15]*d3;
    float s = (accA+accB)+(accC+accD);
    float e2 = __expf(2.f*s);
    float th = 1.f - 2.f*__builtin_amdgcn_rcpf(e2 + 1.f);
    return th + bv*hprev + cv;
}

__global__ __launch_bounds__(256) void scan_k(
    const float* __restrict__ xdbl, const float* __restrict__ dt,
    const float* __restrict__ A, float* __restrict__ hs)
{
    __shared__ float Wrot[16*16*16];   // [p][i][j] in DPP consumption order
    __shared__ float bc[128*32];       // [st][b][32]
    int tid = threadIdx.x;
    int wv = tid >> 6, lane = tid & 63;
    int i = lane & 15;

    // probe: run the exact DPP program on lane index -> column order c[j]
    int c[16];
    {
        int a0 = i;
        int b0 = dppi<0x124>(a0), c0 = dppi<0x128>(a0), d0 = dppi<0x12c>(a0);
        c[0]=a0; c[4]=b0; c[8]=c0; c[12]=d0;
        int a1 = dppi<0x121>(a0), b1 = dppi<0x121>(b0);
        int c1 = dppi<0x121>(c0), d1 = dppi<0x121>(d0);
        c[1]=a1; c[5]=b1; c[9]=c1; c[13]=d1;
        int a2 = dppi<0x121>(a1), b2 = dppi<0x121>(b1);
        int c2 = dppi<0x121>(c1), d2 = dppi<0x121>(d1);
        c[2]=a2; c[6]=b2; c[10]=c2; c[14]=d2;
        int a3 = dppi<0x121>(a2), b3 = dppi<0x121>(b2);
        int c3 = dppi<0x121>(c2), d3 = dppi<0x121>(d2);
        c[3]=a3; c[7]=b3; c[11]=c3; c[15]=d3;
    }
    {   // build Wrot: thread (p = tid>>4, i)
        int p = tid >> 4;
        float dtp = __expf(dt[p]);
        #pragma unroll
        for (int j=0;j<16;++j)
            Wrot[(p*16 + i)*16 + j] = __expf(dtp * A[i*16 + c[j]]);
    }
    __syncthreads();

    float W0[16], W1[16];
    {
        const float4* r4 = (const float4*)&Wrot[(0*16+i)*16];
        float4 w0=r4[0], w1=r4[1], w2=r4[2], w3=r4[3];
        W0[0]=w0.x; W0[1]=w0.y; W0[2]=w0.z; W0[3]=w0.w;
        W0[4]=w1.x; W0[5]=w1.y; W0[6]=w1.z; W0[7]=w1.w;
        W0[8]=w2.x; W0[9]=w2.y; W0[10]=w2.z; W0[11]=w2.w;
        W0[12]=w3.x; W0[13]=w3.y; W0[14]=w3.z; W0[15]=w3.w;
    }
    int b = wv;
    bool proc = (wv < 2);
    bool do_store = proc && (lane < 16);
    float hn = 0.f;

    for (int chunk = 0; chunk < 32; ++chunk){
        #pragma unroll
        for (int t=0;t<16;++t){
            int e = tid + t*256;
            int st = e >> 6, rest = e & 63;
            int bb = rest >> 5, col = rest & 31;
            bc[(st*2+bb)*32 + col] = xdbl[(size_t)(bb*SEQ + chunk*64 + st)*32 + col];
        }
        __syncthreads();
        if (proc){
            float bv = bc[(0*2+b)*32 + i];
            float cv = bc[(0*2+b)*32 + 16 + i];
            size_t hbase = (size_t)(b*SEQ + chunk*64)*16 + i;
            for (int st2 = 0; st2 < 64; st2 += 2){
                // prefetch for step st2+1
                int pn1 = (st2+1)&15;
                float bvn = bc[((st2+1)*2+b)*32 + i];
                float cvn = bc[((st2+1)*2+b)*32 + 16 + i];
                {
                    const float4* r4 = (const float4*)&Wrot[(pn1*16+i)*16];
                    float4 w0=r4[0], w1=r4[1], w2=r4[2], w3=r4[3];
                    W1[0]=w0.x; W1[1]=w0.y; W1[2]=w0.z; W1[3]=w0.w;
                    W1[4]=w1.x; W1[5]=w1.y; W1[6]=w1.z; W1[7]=w1.w;
                    W1[8]=w2.x; W1[9]=w2.y; W1[10]=w2.z; W1[11]=w2.w;
                    W1[12]=w3.x; W1[13]=w3.y; W1[14]=w3.z; W1[15]=w3.w;
                }
                hn = scan_step(hn, W0, bv, cv);
                if (do_store) hs[hbase + (size_t)st2*16] = hn;
                // prefetch for step st2+2 (wraps to p=0 / st=0 at chunk end)
                int pn2 = (st2+2)&15;
                int stn = (st2+2)&63;
                bv = bc[(stn*2+b)*32 + i];
                cv = bc[(stn*2+b)*32 + 16 + i];
                {
                    const float4* r4 = (const float4*)&Wrot[(pn2*16+i)*16];
                    float4 w0=r4[0], w1=r4[1], w2=r4[2], w3=r4[3];
                    W0[0]=w0.x; W0[1]=w0.y; W0[2]=w0.z; W0[3]=w0.w;
                    W0[4]=w1.x; W0[5]=w1.y; W0[6]=w1.z; W0[7]=w1.w;
                    W0[8]=w2.x; W0[9]=w2.y; W0[10]=w2.z; W0[11]=w2.w;
                    W0[12]=w3.x; W0[13]=w3.y; W0[14]=w3.z; W0[15]=w3.w;
                }
                hn = scan_step(hn, W1, bvn, cvn);
                if (do_store) hs[hbase + (size_t)(st2+1)*16] = hn;
            }
        }
        __syncthreads();
    }
}

// ---------------- y = repeat(hs,128) + res (bf16) --------------------------
__global__ __launch_bounds__(256) void y_assemble(
    const float* __restrict__ hs, const unsigned short* __restrict__ xr,
    unsigned short* __restrict__ y)
{
    int idx = blockIdx.x*256 + threadIdx.x;
    int r = idx >> 10;
    int c2 = (idx & 1023)*2;
    unsigned int u = *(const unsigned int*)(xr + (size_t)r*DFF + DINNER + c2);
    float h0 = hs[(size_t)r*16 + (c2 >> 7)];
    float y0 = h0 + b2f(u & 0xffff);
    float y1 = h0 + b2f(u >> 16);
    *(unsigned int*)(y + (size_t)r*DINNER + c2) =
        (unsigned int)f2b(y0) | ((unsigned int)f2b(y1) << 16);
}

// ---------------------------------------------------------------------------
extern "C" void kernel_launch(void* const* d_in, const int* in_sizes, int n_in,
                              void* d_out, int out_size, void* d_ws, size_t ws_size,
                              hipStream_t stream)
{
    (void)in_sizes; (void)n_in; (void)out_size; (void)ws_size;
    const float* x     = (const float*)d_in[0];
    const float* ln1_g = (const float*)d_in[1];
    const float* ln1_b = (const float*)d_in[2];
    const float* Wq    = (const float*)d_in[3];
    const float* bq    = (const float*)d_in[4];
    const float* Wk    = (const float*)d_in[5];
    const float* bk    = (const float*)d_in[6];
    const float* Wv    = (const float*)d_in[7];
    const float* bv    = (const float*)d_in[8];
    const float* Wo    = (const float*)d_in[9];
    const float* bo    = (const float*)d_in[10];
    const float* ln2_g = (const float*)d_in[11];
    const float* ln2_b = (const float*)d_in[12];
    const float* in_w  = (const float*)d_in[13];
    const float* in_b  = (const float*)d_in[14];
    const float* conv_w= (const float*)d_in[15];
    const float* conv_b= (const float*)d_in[16];
    const float* xp_w  = (const float*)d_in[17];
    const float* xp_b  = (const float*)d_in[18];
    const float* dt    = (const float*)d_in[19];
    const float* A     = (const float*)d_in[20];
    const float* out_w = (const float*)d_in[22];
    const float* out_b = (const float*)d_in[23];
    const float* ln3_g = (const float*)d_in[24];
    const float* ln3_b = (const float*)d_in[25];
    const float* fc1_w = (const float*)d_in[26];
    const float* fc1_b = (const float*)d_in[27];
    const float* fc2_w = (const float*)d_in[28];
    const float* fc2_b = (const float*)d_in[29];

    char* ws = (char*)d_ws;
    const size_t MB = 1ull << 20;
    unsigned short* WqT  = (unsigned short*)(ws + 0*MB);
    unsigned short* WkT  = (unsigned short*)(ws + 2*MB);
    unsigned short* WvT  = (unsigned short*)(ws + 4*MB);
    unsigned short* WoT  = (unsigned short*)(ws + 6*MB);
    unsigned short* inT  = (unsigned short*)(ws + 8*MB);
    unsigned short* outT = (unsigned short*)(ws + 16*MB);
    unsigned short* f1T  = (unsigned short*)(ws + 20*MB);
    unsigned short* f2T  = (unsigned short*)(ws + 28*MB);
    unsigned short* hbf  = (unsigned short*)(ws + 36*MB);
    float*          x2   = (float*)(ws + 44*MB);
    float*          x3   = (float*)(ws + 60*MB);
    unsigned short* qb   = (unsigned short*)(ws + 76*MB);
    unsigned short* kb   = (unsigned short*)(ws + 84*MB);
    unsigned short* vb   = (unsigned short*)(ws + 92*MB);
    unsigned short* attnb= (unsigned short*)(ws + 100*MB);
    unsigned short* xr   = (unsigned short*)(ws + 76*MB);   // reuse after attn
    unsigned short* ffn  = (unsigned short*)(ws + 76*MB);   // reuse after y
    unsigned short* xm2  = (unsigned short*)(ws + 108*MB);
    unsigned short* yb   = (unsigned short*)(ws + 108*MB);  // reuse after xp
    float*          xdbl = (float*)(ws + 124*MB);
    float*          hsb  = (float*)(ws + 124*MB + 512*1024);

    dim3 blk(256);
    transpose_cast<<<dim3(16,16), blk, 0, stream>>>(Wq, WqT, 1024, 1024);
    transpose_cast<<<dim3(16,16), blk, 0, stream>>>(Wk, WkT, 1024, 1024);
    transpose_cast<<<dim3(16,16), blk, 0, stream>>>(Wv, WvT, 1024, 1024);
    transpose_cast<<<dim3(16,16), blk, 0, stream>>>(Wo, WoT, 1024, 1024);
    transpose_cast<<<dim3(64,16), blk, 0, stream>>>(in_w, inT, 1024, 4096);
    transpose_cast<<<dim3(16,32), blk, 0, stream>>>(out_w, outT, 2048, 1024);
    transpose_cast<<<dim3(64,16), blk, 0, stream>>>(fc1_w, f1T, 1024, 4096);
    transpose_cast<<<dim3(16,64), blk, 0, stream>>>(fc2_w, f2T, 4096, 1024);

    layernorm_bf16<<<MROWS, blk, 0, stream>>>(x, ln1_g, ln1_b, hbf);
    gemm_bt<1,0,0><<<dim3(8,32),  blk, 0, stream>>>(hbf, WqT, bq, nullptr, qb, 1024, 1024);
    gemm_bt<1,0,0><<<dim3(8,32),  blk, 0, stream>>>(hbf, WkT, bk, nullptr, kb, 1024, 1024);
    gemm_bt<1,0,0><<<dim3(8,32),  blk, 0, stream>>>(hbf, WvT, bv, nullptr, vb, 1024, 1024);
    attn_flash<<<dim3(32,32), blk, 0, stream>>>(qb, kb, vb, attnb);
    gemm_bt<0,1,0><<<dim3(8,32),  blk, 0, stream>>>(attnb, WoT, bo, x, x2, 1024, 1024);
    layernorm_bf16<<<MROWS, blk, 0, stream>>>(x2, ln2_g, ln2_b, hbf);
    gemm_bt<1,0,0><<<dim3(32,32), blk, 0, stream>>>(hbf, inT, in_b, nullptr, xr, 4096, 1024);
    conv_silu<<<16384, blk, 0, stream>>>(xr, conv_w, conv_b, xm2);
    xp_gemm<<<512, blk, 0, stream>>>(xm2, xp_w, xp_b, xdbl);
    scan_k<<<1, blk, 0, stream>>>(xdbl, dt, A, hsb);
    y_assemble<<<16384, blk, 0, stream>>>(hsb, xr, yb);
    gemm_bt<0,1,0><<<dim3(8,32),  blk, 0, stream>>>(yb, outT, out_b, x2, x3, 1024, 2048);
    layernorm_bf16<<<MROWS, blk, 0, stream>>>(x3, ln3_g, ln3_b, hbf);
    gemm_bt<1,0,1><<<dim3(32,32), blk, 0, stream>>>(hbf, f1T, fc1_b, nullptr, ffn, 4096, 1024);
    gemm_bt<0,1,0><<<dim3(8,32),  blk, 0, stream>>>(ffn, f2T, fc2_b, x3, (float*)d_out, 1024, 4096);
}

// Round 3
// 1077.256 us; speedup vs baseline: 1.1710x; 1.0545x over previous
//
#include <hip/hip_runtime.h>
#include <hip/hip_bf16.h>

// ---------------------------------------------------------------------------
// R3 changes vs R2:
//  * scan_k: all 16x16 phase-weight matrices held in VGPRs (no LDS weight
//    reads -> kills the 197k bank conflicts), depth-1 DPP rotation fan
//    (15 independent row_ror:j), b/c prefetched 2 steps ahead, 128-thread
//    block (__launch_bounds__(128,1) -> 512-VGPR budget).
//  * QKV fused into one GEMM (N=3072), bias concat kernel.
// ---------------------------------------------------------------------------

#define SEQ     2048
#define BATCH   2
#define MROWS   4096      // BATCH*SEQ
#define DMODEL  1024
#define DINNER  2048
#define DFF     4096
#define QKVLD   3072

typedef __attribute__((ext_vector_type(8))) short bf16x8;
typedef __attribute__((ext_vector_type(4))) float f32x4;

__device__ __forceinline__ unsigned short f2b(float x){
    __hip_bfloat16 h = __float2bfloat16(x);
    return *reinterpret_cast<unsigned short*>(&h);
}
__device__ __forceinline__ float b2f(unsigned short u){
    __hip_bfloat16 h;
    *reinterpret_cast<unsigned short*>(&h) = u;
    return __bfloat162float(h);
}
__device__ __forceinline__ float gelu_f(float v){
    float u = 0.7978845608f*(v + 0.044715f*v*v*v);
    float e = __expf(2.f*u);
    float th = 1.f - 2.f*__builtin_amdgcn_rcpf(e + 1.f);
    return 0.5f*v*(1.f + th);
}
__device__ __forceinline__ void gload16(const unsigned short* g, unsigned short* l){
    __builtin_amdgcn_global_load_lds(
        (const __attribute__((address_space(1))) void*)g,
        (__attribute__((address_space(3))) void*)l, 16, 0, 0);
}
template<int CTRL>
__device__ __forceinline__ float dppf(float x){
    int r = __builtin_amdgcn_mov_dpp(__builtin_bit_cast(int, x), CTRL, 0xf, 0xf, false);
    return __builtin_bit_cast(float, r);
}
template<int CTRL>
__device__ __forceinline__ int dppi(int x){
    return __builtin_amdgcn_mov_dpp(x, CTRL, 0xf, 0xf, false);
}

// ---------------- transpose + cast: W (KxN f32) -> Wt (NxK bf16) ----------
__global__ __launch_bounds__(256) void transpose_cast(
    const float* __restrict__ W, unsigned short* __restrict__ Wt, int K, int N)
{
    __shared__ float t[64*65];
    int n0 = blockIdx.x*64, k0 = blockIdx.y*64;
    int c = threadIdx.x & 63, r0 = threadIdx.x >> 6;
    #pragma unroll
    for (int rr = 0; rr < 64; rr += 4)
        t[(rr+r0)*65 + c] = W[(size_t)(k0+rr+r0)*N + n0 + c];
    __syncthreads();
    #pragma unroll
    for (int rr = 0; rr < 64; rr += 4)
        Wt[(size_t)(n0+rr+r0)*K + k0 + c] = f2b(t[c*65 + rr + r0]);
}

// ---------------- concat 3 bias vectors --------------------------------
__global__ __launch_bounds__(256) void concat_bias(
    const float* __restrict__ b0, const float* __restrict__ b1,
    const float* __restrict__ b2, float* __restrict__ o)
{
    int t = blockIdx.x*256 + threadIdx.x;
    float v = (t < 1024) ? b0[t] : (t < 2048 ? b1[t-1024] : b2[t-2048]);
    o[t] = v;
}

// ---------------- layernorm row=1024, f32 in -> bf16 out ------------------
__global__ __launch_bounds__(256) void layernorm_bf16(
    const float* __restrict__ x, const float* __restrict__ g,
    const float* __restrict__ b, unsigned short* __restrict__ out)
{
    int row = blockIdx.x;
    const float4* xr = (const float4*)(x + (size_t)row*DMODEL);
    int tid = threadIdx.x;
    float4 xv = xr[tid];
    float s  = xv.x + xv.y + xv.z + xv.w;
    float ss = xv.x*xv.x + xv.y*xv.y + xv.z*xv.z + xv.w*xv.w;
    #pragma unroll
    for (int d = 32; d > 0; d >>= 1){ s += __shfl_xor(s,d); ss += __shfl_xor(ss,d); }
    __shared__ float sm[8];
    int wv = tid>>6, ln = tid&63;
    if (ln == 0){ sm[wv] = s; sm[4+wv] = ss; }
    __syncthreads();
    s  = sm[0]+sm[1]+sm[2]+sm[3];
    ss = sm[4]+sm[5]+sm[6]+sm[7];
    float mean = s*(1.f/DMODEL);
    float var  = ss*(1.f/DMODEL) - mean*mean;
    float rstd = rsqrtf(var + 1e-5f);
    float4 gv = ((const float4*)g)[tid];
    float4 bv = ((const float4*)b)[tid];
    ushort4 o;
    o.x = f2b((xv.x-mean)*rstd*gv.x + bv.x);
    o.y = f2b((xv.y-mean)*rstd*gv.y + bv.y);
    o.z = f2b((xv.z-mean)*rstd*gv.z + bv.z);
    o.w = f2b((xv.w-mean)*rstd*gv.w + bv.w);
    ((ushort4*)(out + (size_t)row*DMODEL))[tid] = o;
}

// ---------------- GEMM: C[M,N] = act(A[M,K] @ Bt[N,K]^T + bias) (+res) ----
// 128x128 tile, 4 waves, each 64x64. BK=64. global_load_lds staging (m97).
template<int OUT_BF16, int HAS_RES, int ACT>
__global__ __launch_bounds__(256,2) void gemm_bt(
    const unsigned short* __restrict__ A, const unsigned short* __restrict__ Bt,
    const float* __restrict__ bias, const float* __restrict__ res,
    void* __restrict__ outp, int Ndim, int Kdim)
{
    __shared__ unsigned short As[128*64];   // unpadded: required by global_load_lds
    __shared__ unsigned short Bs[128*64];
    int tid = threadIdx.x;
    int lane = tid & 63, wv = tid >> 6;
    int l15 = lane & 15, quad = lane >> 4;
    int m0 = blockIdx.y*128, n0 = blockIdx.x*128;
    int mo = (wv>>1)*64, no = (wv&1)*64;
    int rsub = (lane >> 3);          // 0..7
    int cc8  = (lane & 7)*8;         // element col within 64
    f32x4 zz = {0.f,0.f,0.f,0.f};
    f32x4 acc[4][4];
    #pragma unroll
    for (int i=0;i<4;++i)
      #pragma unroll
      for (int j=0;j<4;++j) acc[i][j] = zz;

    for (int k0 = 0; k0 < Kdim; k0 += 64){
        const unsigned short* Ab = A  + (size_t)(m0 + wv*32 + rsub)*Kdim + k0 + cc8;
        const unsigned short* Bb = Bt + (size_t)(n0 + wv*32 + rsub)*Kdim + k0 + cc8;
        #pragma unroll
        for (int i=0;i<4;++i){
            gload16(Ab + (size_t)(i*8)*Kdim, &As[(wv*32 + i*8)*64]);
            gload16(Bb + (size_t)(i*8)*Kdim, &Bs[(wv*32 + i*8)*64]);
        }
        __syncthreads();
        #pragma unroll
        for (int kc=0;kc<2;++kc){
            bf16x8 af[4], bfr[4];
            #pragma unroll
            for (int t=0;t<4;++t){
                af[t]  = *(const bf16x8*)(&As[(mo + t*16 + l15)*64 + kc*32 + quad*8]);
                bfr[t] = *(const bf16x8*)(&Bs[(no + t*16 + l15)*64 + kc*32 + quad*8]);
            }
            #pragma unroll
            for (int mt=0;mt<4;++mt)
              #pragma unroll
              for (int nt=0;nt<4;++nt)
                acc[mt][nt] = __builtin_amdgcn_mfma_f32_16x16x32_bf16(af[mt], bfr[nt], acc[mt][nt], 0,0,0);
        }
        __syncthreads();
    }
    #pragma unroll
    for (int mt=0;mt<4;++mt){
      #pragma unroll
      for (int nt=0;nt<4;++nt){
        int gn = n0 + no + nt*16 + l15;
        float bval = bias[gn];
        #pragma unroll
        for (int r=0;r<4;++r){
            int gm = m0 + mo + mt*16 + quad*4 + r;
            size_t off = (size_t)gm*Ndim + gn;
            float v = acc[mt][nt][r] + bval;
            if constexpr (HAS_RES) v += res[off];
            if constexpr (ACT == 1) v = gelu_f(v);
            if constexpr (OUT_BF16) ((unsigned short*)outp)[off] = f2b(v);
            else                    ((float*)outp)[off] = v;
        }
      }
    }
}

// ---------------- flash attention, causal, 16 heads of 64 ------------------
// q/k/v live in the fused qkv buffer with row stride QKVLD.
__global__ __launch_bounds__(256,2) void attn_flash(
    const unsigned short* __restrict__ qkv, unsigned short* __restrict__ attn)
{
    __shared__ unsigned short Qs[64*72];
    __shared__ unsigned short Ks[64*72];
    __shared__ unsigned short Vt[64*72];
    __shared__ unsigned short Ps[64*72];
    int bh = blockIdx.y;
    int qt = (int)gridDim.x - 1 - (int)blockIdx.x;
    int q0 = qt*64;
    int tid = threadIdx.x, wv = tid>>6, lane = tid&63;
    int l15 = lane&15, quad = lane>>4;
    const size_t basei = (size_t)(bh>>4)*SEQ*QKVLD + (size_t)(bh&15)*64;
    const unsigned short* q = qkv + basei;
    const unsigned short* k = qkv + basei + DMODEL;
    const unsigned short* v = qkv + basei + 2*DMODEL;
    const size_t baseo = (size_t)(bh>>4)*SEQ*DMODEL + (size_t)(bh&15)*64;

    #pragma unroll
    for (int i=0;i<2;++i){
        int cch = tid + i*256; int r = cch>>3, cc = cch&7;
        *(uint4*)(&Qs[r*72 + cc*8]) = *(const uint4*)(q + (size_t)(q0+r)*QKVLD + cc*8);
    }
    __syncthreads();
    bf16x8 aq0 = *(const bf16x8*)(&Qs[(wv*16 + l15)*72 + quad*8]);
    bf16x8 aq1 = *(const bf16x8*)(&Qs[(wv*16 + l15)*72 + 32 + quad*8]);

    float m_i[4], l_i[4];
    f32x4 zz = {0.f,0.f,0.f,0.f};
    f32x4 o[4];
    #pragma unroll
    for (int r=0;r<4;++r){ m_i[r] = -__builtin_inff(); l_i[r] = 0.f; }
    #pragma unroll
    for (int d=0;d<4;++d) o[d] = zz;

    for (int kt = 0; kt <= qt; ++kt){
        int t0 = kt*64;
        #pragma unroll
        for (int i=0;i<2;++i){
            int cch = tid + i*256; int r = cch>>3, cc = cch&7;
            *(uint4*)(&Ks[r*72 + cc*8]) = *(const uint4*)(k + (size_t)(t0+r)*QKVLD + cc*8);
            uint4 vv = *(const uint4*)(v + (size_t)(t0+r)*QKVLD + cc*8);
            const unsigned short* pv = (const unsigned short*)&vv;
            #pragma unroll
            for (int j=0;j<8;++j) Vt[(cc*8+j)*72 + r] = pv[j];
        }
        __syncthreads();

        f32x4 sc[4];
        #pragma unroll
        for (int st=0;st<4;++st){
            bf16x8 b0 = *(const bf16x8*)(&Ks[(st*16+l15)*72 + quad*8]);
            bf16x8 b1 = *(const bf16x8*)(&Ks[(st*16+l15)*72 + 32 + quad*8]);
            sc[st] = __builtin_amdgcn_mfma_f32_16x16x32_bf16(aq0, b0, zz, 0,0,0);
            sc[st] = __builtin_amdgcn_mfma_f32_16x16x32_bf16(aq1, b1, sc[st], 0,0,0);
        }
        bool diag = (kt == qt);
        float sval[4][4];
        float mrow[4];
        #pragma unroll
        for (int r=0;r<4;++r) mrow[r] = -__builtin_inff();
        #pragma unroll
        for (int st=0;st<4;++st)
          #pragma unroll
          for (int r=0;r<4;++r){
            float svv = sc[st][r]*0.125f;
            if (diag && (st*16 + l15 > wv*16 + quad*4 + r)) svv = -__builtin_inff();
            sval[st][r] = svv;
            mrow[r] = fmaxf(mrow[r], svv);
          }
        #pragma unroll
        for (int d=1; d<16; d<<=1)
          #pragma unroll
          for (int r=0;r<4;++r) mrow[r] = fmaxf(mrow[r], __shfl_xor(mrow[r], d));
        float alpha[4], rsum[4];
        #pragma unroll
        for (int r=0;r<4;++r){
            float mn = fmaxf(m_i[r], mrow[r]);
            alpha[r] = __expf(m_i[r] - mn);
            m_i[r] = mn;
        }
        #pragma unroll
        for (int st=0;st<4;++st)
          #pragma unroll
          for (int r=0;r<4;++r) sval[st][r] = __expf(sval[st][r] - m_i[r]);
        #pragma unroll
        for (int r=0;r<4;++r) rsum[r] = sval[0][r]+sval[1][r]+sval[2][r]+sval[3][r];
        #pragma unroll
        for (int d=1; d<16; d<<=1)
          #pragma unroll
          for (int r=0;r<4;++r) rsum[r] += __shfl_xor(rsum[r], d);
        #pragma unroll
        for (int r=0;r<4;++r) l_i[r] = l_i[r]*alpha[r] + rsum[r];
        #pragma unroll
        for (int st=0;st<4;++st)
          #pragma unroll
          for (int r=0;r<4;++r)
            Ps[(wv*16 + quad*4 + r)*72 + st*16 + l15] = f2b(sval[st][r]);
        #pragma unroll
        for (int d=0;d<4;++d)
          #pragma unroll
          for (int r=0;r<4;++r) o[d][r] = o[d][r]*alpha[r];
        __syncthreads();
        bf16x8 ap0 = *(const bf16x8*)(&Ps[(wv*16 + l15)*72 + quad*8]);
        bf16x8 ap1 = *(const bf16x8*)(&Ps[(wv*16 + l15)*72 + 32 + quad*8]);
        #pragma unroll
        for (int dtile=0;dtile<4;++dtile){
            bf16x8 b0 = *(const bf16x8*)(&Vt[(dtile*16+l15)*72 + quad*8]);
            bf16x8 b1 = *(const bf16x8*)(&Vt[(dtile*16+l15)*72 + 32 + quad*8]);
            o[dtile] = __builtin_amdgcn_mfma_f32_16x16x32_bf16(ap0, b0, o[dtile], 0,0,0);
            o[dtile] = __builtin_amdgcn_mfma_f32_16x16x32_bf16(ap1, b1, o[dtile], 0,0,0);
        }
        __syncthreads();
    }
    #pragma unroll
    for (int r=0;r<4;++r){
        float inv = 1.f/l_i[r];
        int gm = q0 + wv*16 + quad*4 + r;
        #pragma unroll
        for (int dtile=0;dtile<4;++dtile)
            attn[baseo + (size_t)gm*DMODEL + dtile*16 + l15] = f2b(o[dtile][r]*inv);
    }
}

// ---------------- depthwise causal conv(4) + bias + silu -------------------
__global__ __launch_bounds__(256) void conv_silu(
    const unsigned short* __restrict__ xr, const float* __restrict__ cw,
    const float* __restrict__ cb, unsigned short* __restrict__ xm2)
{
    int idx = blockIdx.x*256 + threadIdx.x;
    int r  = idx >> 10;
    int c2 = (idx & 1023)*2;
    int s  = r & (SEQ-1);
    float4 w0 = *(const float4*)(cw + c2*4);
    float4 w1 = *(const float4*)(cw + (c2+1)*4);
    float w0a[4] = {w0.x,w0.y,w0.z,w0.w};
    float w1a[4] = {w1.x,w1.y,w1.z,w1.w};
    float a0 = cb[c2], a1 = cb[c2+1];
    const unsigned short* xrow = xr + (size_t)r*DFF + c2;
    #pragma unroll
    for (int j=0;j<4;++j){
        int sp = s - 3 + j;
        if (sp >= 0){
            int off = (j-3)*DFF;
            unsigned int u = *(const unsigned int*)(xrow + off);
            a0 += w0a[j]*b2f(u & 0xffff);
            a1 += w1a[j]*b2f(u >> 16);
        }
    }
    float s0 = a0 * __builtin_amdgcn_rcpf(1.f + __expf(-a0));
    float s1 = a1 * __builtin_amdgcn_rcpf(1.f + __expf(-a1));
    unsigned int op = (unsigned int)f2b(s0) | ((unsigned int)f2b(s1) << 16);
    *(unsigned int*)(xm2 + (size_t)r*DINNER + c2) = op;
}

// ---------------- xdbl = xm2 @ xp_w + xp_b  (N=32, K=2048) -----------------
__global__ __launch_bounds__(256) void xp_gemm(
    const unsigned short* __restrict__ xm2, const float* __restrict__ w,
    const float* __restrict__ bias, float* __restrict__ xdbl)
{
    int tid = threadIdx.x;
    int lr = tid >> 5, n = tid & 31;
    int row = blockIdx.x*8 + lr;
    const unsigned short* ar = xm2 + (size_t)row*DINNER;
    float acc = bias[n];
    #pragma unroll 4
    for (int k2 = 0; k2 < DINNER; k2 += 2){
        unsigned int u = *(const unsigned int*)(ar + k2);
        acc += b2f(u & 0xffff)*w[k2*32 + n] + b2f(u >> 16)*w[(k2+1)*32 + n];
    }
    xdbl[(size_t)row*32 + n] = acc;
}

// ---------------- sequential scan: regs-resident weights, flat DPP ---------
// h_{t+1}[i] = tanh(sum_j exp(dtp*A[i][j]) h_t[j]) + b_t[i]*h_t[i] + c_t[i]
__device__ __forceinline__ float scan_step_flat(float h, const float (&W)[16],
                                                float bv, float cv)
{
    float r1  = dppf<0x121>(h);
    float r2  = dppf<0x122>(h);
    float r3  = dppf<0x123>(h);
    float r4  = dppf<0x124>(h);
    float r5  = dppf<0x125>(h);
    float r6  = dppf<0x126>(h);
    float r7  = dppf<0x127>(h);
    float r8  = dppf<0x128>(h);
    float r9  = dppf<0x129>(h);
    float r10 = dppf<0x12a>(h);
    float r11 = dppf<0x12b>(h);
    float r12 = dppf<0x12c>(h);
    float r13 = dppf<0x12d>(h);
    float r14 = dppf<0x12e>(h);
    float r15 = dppf<0x12f>(h);
    float a0 = W[0]*h;    a0 = fmaf(W[1], r1, a0);  a0 = fmaf(W[2], r2, a0);  a0 = fmaf(W[3], r3, a0);
    float a1 = W[4]*r4;   a1 = fmaf(W[5], r5, a1);  a1 = fmaf(W[6], r6, a1);  a1 = fmaf(W[7], r7, a1);
    float a2 = W[8]*r8;   a2 = fmaf(W[9], r9, a2);  a2 = fmaf(W[10],r10,a2);  a2 = fmaf(W[11],r11,a2);
    float a3 = W[12]*r12; a3 = fmaf(W[13],r13,a3);  a3 = fmaf(W[14],r14,a3);  a3 = fmaf(W[15],r15,a3);
    float s = (a0+a1)+(a2+a3);
    float e2 = __expf(2.f*s);
    float th = 1.f - 2.f*__builtin_amdgcn_rcpf(e2 + 1.f);
    return th + fmaf(bv, h, cv);
}

__global__ __launch_bounds__(128,1) void scan_k(
    const float* __restrict__ xdbl, const float* __restrict__ dt,
    const float* __restrict__ A, float* __restrict__ hs)
{
    __shared__ float bc[2][66*32];    // per-wave staging, 2 rows of pad
    int tid = threadIdx.x;
    int wv = tid >> 6, lane = tid & 63;
    int i = lane & 15;
    int b = wv;

    // probe: identical DPP fan applied to lane index -> source-lane order
    int c[16];
    c[0]  = i;
    c[1]  = dppi<0x121>(i);
    c[2]  = dppi<0x122>(i);
    c[3]  = dppi<0x123>(i);
    c[4]  = dppi<0x124>(i);
    c[5]  = dppi<0x125>(i);
    c[6]  = dppi<0x126>(i);
    c[7]  = dppi<0x127>(i);
    c[8]  = dppi<0x128>(i);
    c[9]  = dppi<0x129>(i);
    c[10] = dppi<0x12a>(i);
    c[11] = dppi<0x12b>(i);
    c[12] = dppi<0x12c>(i);
    c[13] = dppi<0x12d>(i);
    c[14] = dppi<0x12e>(i);
    c[15] = dppi<0x12f>(i);

    float Wreg[16][16];               // all 16 phases resident in VGPRs
    #pragma unroll
    for (int p=0;p<16;++p){
        float dtp = __expf(dt[p]);
        #pragma unroll
        for (int j=0;j<16;++j)
            Wreg[p][j] = __expf(dtp * A[i*16 + c[j]]);
    }

    float hn = 0.f;
    for (int chunk = 0; chunk < 32; ++chunk){
        const float4* src = (const float4*)(xdbl + (size_t)(b*SEQ + chunk*64)*32);
        float* dstw = bc[wv];
        #pragma unroll
        for (int t=0;t<8;++t)
            ((float4*)dstw)[lane + t*64] = src[lane + t*64];
        __syncthreads();
        float bv0 = dstw[0*32 + i],  cv0 = dstw[0*32 + 16 + i];
        float bv1 = dstw[1*32 + i],  cv1 = dstw[1*32 + 16 + i];
        size_t hbase = (size_t)(b*SEQ + chunk*64)*16 + i;
        #pragma unroll
        for (int st16=0; st16<4; ++st16){
            #pragma unroll
            for (int p=0; p<16; p+=2){
                int st = st16*16 + p;
                hn = scan_step_flat(hn, Wreg[p], bv0, cv0);
                if (lane < 16) hs[hbase + (size_t)st*16] = hn;
                bv0 = dstw[(st+2)*32 + i]; cv0 = dstw[(st+2)*32 + 16 + i];
                hn = scan_step_flat(hn, Wreg[p+1], bv1, cv1);
                if (lane < 16) hs[hbase + (size_t)(st+1)*16] = hn;
                bv1 = dstw[(st+3)*32 + i]; cv1 = dstw[(st+3)*32 + 16 + i];
            }
        }
        __syncthreads();
    }
}

// ---------------- y = repeat(hs,128) + res (bf16) --------------------------
__global__ __launch_bounds__(256) void y_assemble(
    const float* __restrict__ hs, const unsigned short* __restrict__ xr,
    unsigned short* __restrict__ y)
{
    int idx = blockIdx.x*256 + threadIdx.x;
    int r = idx >> 10;
    int c2 = (idx & 1023)*2;
    unsigned int u = *(const unsigned int*)(xr + (size_t)r*DFF + DINNER + c2);
    float h0 = hs[(size_t)r*16 + (c2 >> 7)];
    float y0 = h0 + b2f(u & 0xffff);
    float y1 = h0 + b2f(u >> 16);
    *(unsigned int*)(y + (size_t)r*DINNER + c2) =
        (unsigned int)f2b(y0) | ((unsigned int)f2b(y1) << 16);
}

// ---------------------------------------------------------------------------
extern "C" void kernel_launch(void* const* d_in, const int* in_sizes, int n_in,
                              void* d_out, int out_size, void* d_ws, size_t ws_size,
                              hipStream_t stream)
{
    (void)in_sizes; (void)n_in; (void)out_size; (void)ws_size;
    const float* x     = (const float*)d_in[0];
    const float* ln1_g = (const float*)d_in[1];
    const float* ln1_b = (const float*)d_in[2];
    const float* Wq    = (const float*)d_in[3];
    const float* bq    = (const float*)d_in[4];
    const float* Wk    = (const float*)d_in[5];
    const float* bk    = (const float*)d_in[6];
    const float* Wv    = (const float*)d_in[7];
    const float* bv    = (const float*)d_in[8];
    const float* Wo    = (const float*)d_in[9];
    const float* bo    = (const float*)d_in[10];
    const float* ln2_g = (const float*)d_in[11];
    const float* ln2_b = (const float*)d_in[12];
    const float* in_w  = (const float*)d_in[13];
    const float* in_b  = (const float*)d_in[14];
    const float* conv_w= (const float*)d_in[15];
    const float* conv_b= (const float*)d_in[16];
    const float* xp_w  = (const float*)d_in[17];
    const float* xp_b  = (const float*)d_in[18];
    const float* dt    = (const float*)d_in[19];
    const float* A     = (const float*)d_in[20];
    const float* out_w = (const float*)d_in[22];
    const float* out_b = (const float*)d_in[23];
    const float* ln3_g = (const float*)d_in[24];
    const float* ln3_b = (const float*)d_in[25];
    const float* fc1_w = (const float*)d_in[26];
    const float* fc1_b = (const float*)d_in[27];
    const float* fc2_w = (const float*)d_in[28];
    const float* fc2_b = (const float*)d_in[29];

    char* ws = (char*)d_ws;
    const size_t MB = 1ull << 20;
    unsigned short* qkvT = (unsigned short*)(ws + 0*MB);   // WqT|WkT|WvT, 6MB
    unsigned short* WoT  = (unsigned short*)(ws + 6*MB);
    unsigned short* inT  = (unsigned short*)(ws + 8*MB);
    unsigned short* outT = (unsigned short*)(ws + 16*MB);
    unsigned short* f1T  = (unsigned short*)(ws + 20*MB);
    unsigned short* f2T  = (unsigned short*)(ws + 28*MB);
    unsigned short* hbf  = (unsigned short*)(ws + 36*MB);
    float*          x2   = (float*)(ws + 44*MB);
    float*          x3   = (float*)(ws + 60*MB);
    unsigned short* qkv  = (unsigned short*)(ws + 76*MB);  // 24MB fused QKV
    unsigned short* attnb= (unsigned short*)(ws + 100*MB);
    unsigned short* xr   = (unsigned short*)(ws + 76*MB);  // reuse after attn
    unsigned short* ffn  = (unsigned short*)(ws + 76*MB);  // reuse after y
    unsigned short* xm2  = (unsigned short*)(ws + 108*MB);
    unsigned short* yb   = (unsigned short*)(ws + 108*MB); // reuse after xp
    float*          xdbl = (float*)(ws + 124*MB);
    float*          hsb  = (float*)(ws + 124*MB + 512*1024);
    float*          bqkv = (float*)(ws + 125*MB);

    dim3 blk(256);
    transpose_cast<<<dim3(16,16), blk, 0, stream>>>(Wq, qkvT,              1024, 1024);
    transpose_cast<<<dim3(16,16), blk, 0, stream>>>(Wk, qkvT + 1024*1024,  1024, 1024);
    transpose_cast<<<dim3(16,16), blk, 0, stream>>>(Wv, qkvT + 2*1024*1024,1024, 1024);
    transpose_cast<<<dim3(16,16), blk, 0, stream>>>(Wo, WoT, 1024, 1024);
    transpose_cast<<<dim3(64,16), blk, 0, stream>>>(in_w, inT, 1024, 4096);
    transpose_cast<<<dim3(16,32), blk, 0, stream>>>(out_w, outT, 2048, 1024);
    transpose_cast<<<dim3(64,16), blk, 0, stream>>>(fc1_w, f1T, 1024, 4096);
    transpose_cast<<<dim3(16,64), blk, 0, stream>>>(fc2_w, f2T, 4096, 1024);
    concat_bias<<<12, blk, 0, stream>>>(bq, bk, bv, bqkv);

    layernorm_bf16<<<MROWS, blk, 0, stream>>>(x, ln1_g, ln1_b, hbf);
    gemm_bt<1,0,0><<<dim3(24,32), blk, 0, stream>>>(hbf, qkvT, bqkv, nullptr, qkv, QKVLD, 1024);
    attn_flash<<<dim3(32,32), blk, 0, stream>>>(qkv, attnb);
    gemm_bt<0,1,0><<<dim3(8,32),  blk, 0, stream>>>(attnb, WoT, bo, x, x2, 1024, 1024);
    layernorm_bf16<<<MROWS, blk, 0, stream>>>(x2, ln2_g, ln2_b, hbf);
    gemm_bt<1,0,0><<<dim3(32,32), blk, 0, stream>>>(hbf, inT, in_b, nullptr, xr, 4096, 1024);
    conv_silu<<<16384, blk, 0, stream>>>(xr, conv_w, conv_b, xm2);
    xp_gemm<<<512, blk, 0, stream>>>(xm2, xp_w, xp_b, xdbl);
    scan_k<<<1, dim3(128), 0, stream>>>(xdbl, dt, A, hsb);
    y_assemble<<<16384, blk, 0, stream>>>(hsb, xr, yb);
    gemm_bt<0,1,0><<<dim3(8,32),  blk, 0, stream>>>(yb, outT, out_b, x2, x3, 1024, 2048);
    layernorm_bf16<<<MROWS, blk, 0, stream>>>(x3, ln3_g, ln3_b, hbf);
    gemm_bt<1,0,1><<<dim3(32,32), blk, 0, stream>>>(hbf, f1T, fc1_b, nullptr, ffn, 4096, 1024);
    gemm_bt<0,1,0><<<dim3(8,32),  blk, 0, stream>>>(ffn, f2T, fc2_b, x3, (float*)d_out, 1024, 4096);
}